// Round 8
// baseline (357.672 us; speedup 1.0000x reference)
//
#include <hip/hip_runtime.h>
#include <hip/hip_bf16.h>

typedef __bf16 bf16;
typedef __bf16 v8bf __attribute__((ext_vector_type(8)));
typedef float f32x4 __attribute__((ext_vector_type(4)));

#define BB 16
#define CCH 128
#define HH 96
#define WW 96
#define EE 6
#define HP 98

static constexpr size_t XP_ELEMS   = (size_t)BB * HP * HP * CCH;   // padded x, bf16 channel-last
static constexpr size_t WT1S_ELEMS = (size_t)EE * 36 * 4096;       // [e][q*9+tap][128 row][32 cin] swizzled
static constexpr size_t WT2S_ELEMS = (size_t)EE * 4 * 4096;        // [e][kc][128 row][32 cin] swizzled
static constexpr size_t XP_BYTES   = XP_ELEMS * 2;
static constexpr size_t WT1S_BYTES = WT1S_ELEMS * 2;
static constexpr size_t WT2S_BYTES = WT2S_ELEMS * 2;

__device__ inline bf16 to_bf16(float f) { return (bf16)f; }

// async global->LDS, 16B/lane; LDS dest must be WAVE-UNIFORM (HW adds lane*16)
__device__ __forceinline__ void gload16(const bf16* gsrc, bf16* ldst_wave_uniform) {
    __builtin_amdgcn_global_load_lds(
        (const __attribute__((address_space(1))) unsigned int*)gsrc,
        (__attribute__((address_space(3))) unsigned int*)ldst_wave_uniform, 16, 0, 0);
}

// full-bank XOR swizzle over the 4 granule slots
__device__ __forceinline__ int fsw(int r) { return (r & 3) ^ ((r >> 2) & 3); }

// ---------------- zero the 1-px halo of xp ----------------
__global__ void border_kernel(bf16* __restrict__ xp) {
    const int b = blockIdx.x;
    bf16* xpb = xp + (size_t)b * HP * HP * CCH;
    uint4 z; z.x = z.y = z.z = z.w = 0u;
    for (int k = threadIdx.x; k < 388 * 16; k += 256) {
        int cell = k >> 4, gci = k & 15;
        int y, xx;
        if      (cell < 98)  { y = 0;              xx = cell; }
        else if (cell < 196) { y = 97;             xx = cell - 98; }
        else if (cell < 292) { y = cell - 196 + 1; xx = 0; }
        else                 { y = cell - 292 + 1; xx = 97; }
        *reinterpret_cast<uint4*>(xpb + ((size_t)y * HP + xx) * CCH + gci * 8) = z;
    }
}

// ---------------- pad + layout transform + per-(b,y) channel row sums ----------------
__global__ void pad_kernel(const float* __restrict__ x, bf16* __restrict__ xp,
                           float* __restrict__ meanpart) {
    __shared__ float tile[WW][CCH + 2];
    __shared__ float part[2][CCH];
    const int y = blockIdx.x;
    const int b = blockIdx.y;
    const int t = threadIdx.x;
    const float* src = x + (size_t)b * CCH * HH * WW + (size_t)y * WW;
    for (int i = t; i < CCH * WW; i += 256) {
        int c = i / WW;
        int xx = i - c * WW;
        tile[xx][c] = src[(size_t)c * HH * WW + xx];
    }
    __syncthreads();
    bf16* dst = xp + (((size_t)b * HP + (y + 1)) * HP + 1) * CCH;
    for (int j = t; j < WW * CCH; j += 256) {
        int xx = j >> 7;
        int c = j & 127;
        dst[(size_t)xx * CCH + c] = to_bf16(tile[xx][c]);
    }
    const int c = t & 127, half = t >> 7;
    float s = 0.f;
    for (int xx = half * 48; xx < half * 48 + 48; ++xx) s += tile[xx][c];
    part[half][c] = s;
    __syncthreads();
    if (t < 128) meanpart[((size_t)b * HH + y) * CCH + t] = part[0][t] + part[1][t];
}

__global__ void reduce_mean_kernel(const float* __restrict__ meanpart, float* __restrict__ meanbc) {
    int bc = blockIdx.x * 256 + threadIdx.x;     // < 2048
    int b = bc >> 7, c = bc & 127;
    float s = 0.f;
    for (int y = 0; y < HH; ++y) s += meanpart[((size_t)b * HH + y) * CCH + c];
    meanbc[bc] = s * (1.f / (HH * WW));
}

// ---------------- weight transform into swizzled chunk layouts ----------------
__global__ void wt_kernel(const float* __restrict__ w1, const float* __restrict__ w2,
                          bf16* __restrict__ wt1s, bf16* __restrict__ wt2s) {
    const int idx = blockIdx.x * 256 + threadIdx.x;
    const int W1N = (int)WT1S_ELEMS;
    if (idx < W1N) {
        int o = idx & 4095;
        int lo = o & 7, gs = (o >> 3) & 3, row = o >> 5;
        int cg = idx >> 12;                 // 0..215
        int e = cg / 36, c = cg - e * 36;
        int q = c / 9, tap = c - q * 9;
        int g = gs ^ ((row & 3) ^ ((row >> 2) & 3));
        int cin = q * 32 + g * 8 + lo;
        wt1s[idx] = to_bf16(w1[((size_t)(e * CCH + row) * CCH + cin) * 9 + tap]);
    } else if (idx < W1N + (int)WT2S_ELEMS) {
        int j2 = idx - W1N;
        int o = j2 & 4095;
        int lo = o & 7, gs = (o >> 3) & 3, row = o >> 5;
        int cg = j2 >> 12;                  // 0..23
        int e = cg >> 2, kc = cg & 3;
        int g = gs ^ ((row & 3) ^ ((row >> 2) & 3));
        int cin = kc * 32 + g * 8 + lo;
        wt2s[j2] = to_bf16(w2[(size_t)(e * CCH + row) * CCH + cin]);
    }
}

// ---------------- router: parallel logits, then per-b softmax/top-2 (f64, semantics preserved) ----------------
__global__ void router_kernel(const float* __restrict__ meanbc, const float* __restrict__ Wr,
                              const float* __restrict__ br, int* __restrict__ eidx,
                              float* __restrict__ gval, float* __restrict__ total_out) {
    __shared__ double logits_s[BB][EE];
    __shared__ double probs[BB][EE];
    const int t = threadIdx.x;
    if (t < BB * EE) {
        const int b = t / EE, e = t - (t / EE) * EE;
        double s = (double)br[e];
        for (int c = 0; c < CCH; ++c)
            s += (double)meanbc[b * CCH + c] * (double)Wr[c * EE + e];
        if (s > 10.0) s = 10.0;
        if (s < -10.0) s = -10.0;
        logits_s[b][e] = s;
    }
    __syncthreads();
    if (t < BB) {
        const int b = t;
        double mx = logits_s[b][0];
        for (int e = 1; e < EE; ++e) mx = fmax(mx, logits_s[b][e]);
        double den = 0.0, p[EE];
        for (int e = 0; e < EE; ++e) { p[e] = exp(logits_s[b][e] - mx); den += p[e]; }
        for (int e = 0; e < EE; ++e) {
            p[e] /= den;
            if (p[e] < 1e-6) p[e] = 1e-6;
            if (p[e] > 1.0)  p[e] = 1.0;
            probs[b][e] = p[e];
        }
        int e0 = 0;
        for (int e = 1; e < EE; ++e) if (p[e] > p[e0]) e0 = e;
        int e1 = (e0 == 0) ? 1 : 0;
        for (int e = 0; e < EE; ++e) if (e != e0 && p[e] > p[e1]) e1 = e;
        double s2 = p[e0] + p[e1] + 1e-8;
        eidx[b * 2 + 0] = e0;
        eidx[b * 2 + 1] = e1;
        gval[b * 2 + 0] = (float)(p[e0] / s2);
        gval[b * 2 + 1] = (float)(p[e1] / s2);
    }
    __syncthreads();
    if (t == 0) {
        double usage[EE] = {0, 0, 0, 0, 0, 0};
        double ent = 0.0;
        for (int b = 0; b < BB; ++b) {
            double eb = 0.0;
            for (int e = 0; e < EE; ++e) {
                double pv = probs[b][e];
                usage[e] += pv;
                eb -= pv * log(pv + 1e-10);
            }
            ent += eb;
        }
        ent /= (double)BB;
        double lb = 0.0;
        for (int e = 0; e < EE; ++e) {
            double u = usage[e] / (double)BB - 1.0 / (double)EE;
            lb += u * u;
        }
        *total_out = (float)(lb * 5e-4 - ent * 1e-3);
    }
}

// ---------------- fused MoE conv block ----------------
// R8: A-operands DIRECT global->register (L2-hot via XCD swizzle) — no Abuf, no chunk
// stream, no manual waitcnt. 256 thr = 4 waves (2x2), wave = 64 cout x 64 pos,
// acc[4][4]+acc1[4][4] in AGPRs (128) + ~90 arch VGPR -> 2 blocks/CU, no spill.
// Tap loop is barrier-free; compiler software-pipelines. __syncthreads only at
// section/gelu boundaries (10 total) — also drains patch DMA (no asm vmcnt).
__launch_bounds__(256, 2)
__global__ void moe_conv_kernel(const float* __restrict__ x, const bf16* __restrict__ xp,
                                const bf16* __restrict__ wt1s, const bf16* __restrict__ wt2s,
                                const float* __restrict__ b1, const float* __restrict__ b2,
                                const int* __restrict__ eidx, const float* __restrict__ gval,
                                float* __restrict__ out) {
    __shared__ __align__(16) bf16 Patch[2][180 * 32];   // 23040 B
    __shared__ __align__(16) bf16 Ht[128 * 128];        // 32768 B -> 55808 B total, 2 blocks/CU

    // XCD-aware remap: wgid round-robins XCDs; each XCD owns 2 consecutive b's
    const int wgid = blockIdx.x;                 // 0..1151
    const int work = (wgid & 7) * 144 + (wgid >> 3);
    const int b = work / 72;
    const int tile = work - b * 72;
    const int ty = tile / 6, tx = tile - ty * 6;
    const int y0 = ty * 8, x0 = tx * 16;

    const int t = threadIdx.x;
    const int lane = t & 63;
    const int w = t >> 6;                  // 0..3
    const int wm = w >> 1, wn = w & 1;
    const int lr = lane & 15;
    const int lh = lane >> 4;              // 0..3
    const int lq = lh * 4;

    const bf16* xpb = xp + (size_t)b * HP * HP * CCH;
    const int e0 = eidx[b * 2 + 0], e1 = eidx[b * 2 + 1];
    const float g0 = gval[b * 2 + 0], g1 = gval[b * 2 + 1];

    auto patch_dma = [&](int qn, int pb) {           // 3 gload16 / wave (it=2 partial)
        bf16* base = &Patch[pb][0];
        #pragma unroll
        for (int it = 0; it < 3; ++it) {
            int m = it * 256 + t;
            if (m < 720) {
                int rp = m >> 2, sl = m & 3;
                int g = sl ^ fsw(rp);
                int py = rp / 18, px = rp - py * 18;
                gload16(xpb + ((size_t)(y0 + py) * HP + (x0 + px)) * CCH + qn * 32 + g * 8,
                        base + (it * 256 + w * 64) * 8);
            }
        }
    };

    f32x4 acc1[4][4];
    #pragma unroll
    for (int i = 0; i < 4; ++i)
        #pragma unroll
        for (int j = 0; j < 4; ++j) { f32x4 z = {0.f,0.f,0.f,0.f}; acc1[i][j] = z; }

    patch_dma(0, 0);
    __syncthreads();                 // patch(sec 0) resident

    for (int kk2 = 0; kk2 < 2; ++kk2) {
        const int e = kk2 ? e1 : e0;
        const float g = kk2 ? g1 : g0;

        f32x4 acc[4][4];
        #pragma unroll
        for (int i = 0; i < 4; ++i)
            #pragma unroll
            for (int j = 0; j < 4; ++j) { f32x4 z = {0.f,0.f,0.f,0.f}; acc[i][j] = z; }

        // ---- conv3x3: 8 barrier-free 9-tap sections across both experts ----
        for (int q = 0; q < 4; ++q) {
            const int s = kk2 * 4 + q;
            if (s < 7) patch_dma((q + 1) & 3, (s + 1) & 1);    // next section's patch, other buffer
            const bf16* pb = &Patch[s & 1][0];
            const bf16* wb = wt1s + ((size_t)e * 36 + q * 9) * 4096;
            #pragma unroll
            for (int tap = 0; tap < 9; ++tap) {
                const int ry = tap / 3, sx = tap - (tap / 3) * 3;
                const bf16* wc = wb + tap * 4096;
                v8bf af[4], bv[4];
                #pragma unroll
                for (int i = 0; i < 4; ++i) {                  // A: global->reg, coalesced 16B/lane
                    int r = wm * 64 + i * 16 + lr;
                    af[i] = *reinterpret_cast<const v8bf*>(&wc[r * 32 + ((lh ^ fsw(r)) << 3)]);
                }
                #pragma unroll
                for (int j = 0; j < 4; ++j) {                  // B: LDS patch
                    int rp = (wn * 4 + j + ry) * 18 + lr + sx;
                    bv[j] = *reinterpret_cast<const v8bf*>(&pb[rp * 32 + ((lh ^ fsw(rp)) << 3)]);
                }
                #pragma unroll
                for (int i = 0; i < 4; ++i)
                    #pragma unroll
                    for (int j = 0; j < 4; ++j)
                        acc[i][j] = __builtin_amdgcn_mfma_f32_16x16x32_bf16(af[i], bv[j], acc[i][j], 0, 0, 0);
            }
            __syncthreads();         // section end: patch reads done + next patch DMA drained
        }

        // ---- gelu(acc + b1) * g -> Ht (acc dies) ----
        const float* b1e = b1 + e * CCH;
        #pragma unroll
        for (int i = 0; i < 4; ++i) {
            const int cb = wm * 64 + i * 16 + lq;
            float bias[4];
            #pragma unroll
            for (int q2 = 0; q2 < 4; ++q2) bias[q2] = b1e[cb + q2];
            #pragma unroll
            for (int j = 0; j < 4; ++j) {
                const int pos = wn * 64 + j * 16 + lr;
                bf16 hv[4];
                #pragma unroll
                for (int q2 = 0; q2 < 4; ++q2) {
                    float v = acc[i][j][q2] + bias[q2];
                    float u = 0.7978845608028654f * (v + 0.044715f * v * v * v);
                    float ex = __expf(2.f * u);
                    float th = (ex - 1.f) / (ex + 1.f);
                    hv[q2] = to_bf16(g * (0.5f * v * (1.f + th)));
                }
                const int slot = (cb >> 3) ^ (pos & 7);
                *reinterpret_cast<uint2*>(&Ht[pos * 128 + slot * 8 + (cb & 7)]) =
                    *reinterpret_cast<uint2*>(hv);
            }
        }
        __syncthreads();             // publish Ht

        // ---- conv1x1: barrier-free, A global->reg, B from Ht ----
        const bf16* w2b = wt2s + (size_t)e * 4 * 4096;
        #pragma unroll
        for (int kc = 0; kc < 4; ++kc) {
            const bf16* wc = w2b + kc * 4096;
            v8bf af[4], bv[4];
            #pragma unroll
            for (int i = 0; i < 4; ++i) {
                int r = wm * 64 + i * 16 + lr;
                af[i] = *reinterpret_cast<const v8bf*>(&wc[r * 32 + ((lh ^ fsw(r)) << 3)]);
            }
            #pragma unroll
            for (int j = 0; j < 4; ++j) {
                int pos = wn * 64 + j * 16 + lr;
                int gr = kc * 4 + lh;
                bv[j] = *reinterpret_cast<const v8bf*>(&Ht[pos * 128 + ((gr ^ (pos & 7)) << 3)]);
            }
            #pragma unroll
            for (int i = 0; i < 4; ++i)
                #pragma unroll
                for (int j = 0; j < 4; ++j)
                    acc1[i][j] = __builtin_amdgcn_mfma_f32_16x16x32_bf16(af[i], bv[j], acc1[i][j], 0, 0, 0);
        }
        // no barrier needed here: expert-1's section barriers precede its Ht overwrite
    }

    // ---- epilogue: out = acc1 + (g0*b2[e0] + g1*b2[e1]) + (g0+g1)*x ----
    const float gsum = g0 + g1;
    #pragma unroll
    for (int i = 0; i < 4; ++i) {
        const int cb = wm * 64 + i * 16 + lq;
        float bs[4];
        #pragma unroll
        for (int q2 = 0; q2 < 4; ++q2)
            bs[q2] = g0 * b2[e0 * CCH + cb + q2] + g1 * b2[e1 * CCH + cb + q2];
        #pragma unroll
        for (int j = 0; j < 4; ++j) {
            const int pos = wn * 64 + j * 16 + lr;
            const int yy = pos >> 4, xx = pos & 15;
            #pragma unroll
            for (int q2 = 0; q2 < 4; ++q2) {
                size_t gi = (((size_t)b * CCH + cb + q2) * HH + (y0 + yy)) * WW + (x0 + xx);
                out[gi] = acc1[i][j][q2] + bs[q2] + gsum * x[gi];
            }
        }
    }
}

extern "C" void kernel_launch(void* const* d_in, const int* in_sizes, int n_in,
                              void* d_out, int out_size, void* d_ws, size_t ws_size,
                              hipStream_t stream) {
    const float* x  = (const float*)d_in[0];
    const float* Wr = (const float*)d_in[1];
    const float* br = (const float*)d_in[2];
    const float* W1 = (const float*)d_in[3];
    const float* b1 = (const float*)d_in[4];
    const float* W2 = (const float*)d_in[5];
    const float* b2 = (const float*)d_in[6];
    float* out = (float*)d_out;

    char* ws = (char*)d_ws;
    bf16* xp    = (bf16*)ws;
    bf16* wt1s  = (bf16*)(ws + XP_BYTES);
    bf16* wt2s  = (bf16*)(ws + XP_BYTES + WT1S_BYTES);
    float* meanpart = (float*)(ws + XP_BYTES + WT1S_BYTES + WT2S_BYTES);
    float* meanbc   = (float*)(ws + XP_BYTES + WT1S_BYTES + WT2S_BYTES + (size_t)BB * HH * CCH * 4);
    int*   eidx     = (int*)(ws + XP_BYTES + WT1S_BYTES + WT2S_BYTES + (size_t)BB * HH * CCH * 4 + BB * CCH * 4);
    float* gvals    = (float*)(ws + XP_BYTES + WT1S_BYTES + WT2S_BYTES + (size_t)BB * HH * CCH * 4 + BB * CCH * 4 + BB * 2 * 4);
    float* total    = out + (size_t)BB * CCH * HH * WW;

    border_kernel<<<BB, 256, 0, stream>>>(xp);
    pad_kernel<<<dim3(HH, BB), 256, 0, stream>>>(x, xp, meanpart);
    reduce_mean_kernel<<<8, 256, 0, stream>>>(meanpart, meanbc);
    wt_kernel<<<(unsigned)((WT1S_ELEMS + WT2S_ELEMS + 255) / 256), 256, 0, stream>>>(W1, W2, wt1s, wt2s);
    router_kernel<<<1, 128, 0, stream>>>(meanbc, Wr, br, eidx, gvals, total);
    moe_conv_kernel<<<1152, 256, 0, stream>>>(x, xp, wt1s, wt2s, b1, b2, eidx, gvals, out);
}

// Round 10
// 210.544 us; speedup vs baseline: 1.6988x; 1.6988x over previous
//
#include <hip/hip_runtime.h>
#include <hip/hip_bf16.h>

typedef __bf16 bf16;
typedef __bf16 v8bf __attribute__((ext_vector_type(8)));
typedef float f32x4 __attribute__((ext_vector_type(4)));

#define BB 16
#define CCH 128
#define HH 96
#define WW 96
#define EE 6
#define HP 98

static constexpr size_t XP_ELEMS   = (size_t)BB * HP * HP * CCH;   // padded x, bf16 channel-last
static constexpr size_t WT1R_ELEMS = (size_t)EE * 36 * 4096;       // [e][q*9+tap][frag-contig 4096]
static constexpr size_t WT2R_ELEMS = (size_t)EE * 4 * 4096;        // [e][kc][frag-contig 4096]
static constexpr size_t XP_BYTES   = XP_ELEMS * 2;
static constexpr size_t WT1R_BYTES = WT1R_ELEMS * 2;
static constexpr size_t WT2R_BYTES = WT2R_ELEMS * 2;

__device__ inline bf16 to_bf16(float f) { return (bf16)f; }

// async global->LDS, 16B/lane; LDS dest must be WAVE-UNIFORM (HW adds lane*16)
__device__ __forceinline__ void gload16(const bf16* gsrc, bf16* ldst_wave_uniform) {
    __builtin_amdgcn_global_load_lds(
        (const __attribute__((address_space(1))) unsigned int*)gsrc,
        (__attribute__((address_space(3))) unsigned int*)ldst_wave_uniform, 16, 0, 0);
}

// full-bank XOR swizzle over the 4 granule slots (Patch only)
__device__ __forceinline__ int fsw(int r) { return (r & 3) ^ ((r >> 2) & 3); }

#define WAITVM0 asm volatile("s_waitcnt vmcnt(0)" ::: "memory")

// ---------------- zero the 1-px halo of xp ----------------
__global__ void border_kernel(bf16* __restrict__ xp) {
    const int b = blockIdx.x;
    bf16* xpb = xp + (size_t)b * HP * HP * CCH;
    uint4 z; z.x = z.y = z.z = z.w = 0u;
    for (int k = threadIdx.x; k < 388 * 16; k += 256) {
        int cell = k >> 4, gci = k & 15;
        int y, xx;
        if      (cell < 98)  { y = 0;              xx = cell; }
        else if (cell < 196) { y = 97;             xx = cell - 98; }
        else if (cell < 292) { y = cell - 196 + 1; xx = 0; }
        else                 { y = cell - 292 + 1; xx = 97; }
        *reinterpret_cast<uint4*>(xpb + ((size_t)y * HP + xx) * CCH + gci * 8) = z;
    }
}

// ---------------- pad + layout transform + per-(b,y) channel row sums ----------------
__global__ void pad_kernel(const float* __restrict__ x, bf16* __restrict__ xp,
                           float* __restrict__ meanpart) {
    __shared__ float tile[WW][CCH + 2];
    __shared__ float part[2][CCH];
    const int y = blockIdx.x;
    const int b = blockIdx.y;
    const int t = threadIdx.x;
    const float* src = x + (size_t)b * CCH * HH * WW + (size_t)y * WW;
    for (int i = t; i < CCH * WW; i += 256) {
        int c = i / WW;
        int xx = i - c * WW;
        tile[xx][c] = src[(size_t)c * HH * WW + xx];
    }
    __syncthreads();
    bf16* dst = xp + (((size_t)b * HP + (y + 1)) * HP + 1) * CCH;
    for (int j = t; j < WW * CCH; j += 256) {
        int xx = j >> 7;
        int c = j & 127;
        dst[(size_t)xx * CCH + c] = to_bf16(tile[xx][c]);
    }
    const int c = t & 127, half = t >> 7;
    float s = 0.f;
    for (int xx = half * 48; xx < half * 48 + 48; ++xx) s += tile[xx][c];
    part[half][c] = s;
    __syncthreads();
    if (t < 128) meanpart[((size_t)b * HH + y) * CCH + t] = part[0][t] + part[1][t];
}

__global__ void reduce_mean_kernel(const float* __restrict__ meanpart, float* __restrict__ meanbc) {
    int bc = blockIdx.x * 256 + threadIdx.x;     // < 2048
    int b = bc >> 7, c = bc & 127;
    float s = 0.f;
    for (int y = 0; y < HH; ++y) s += meanpart[((size_t)b * HH + y) * CCH + c];
    meanbc[bc] = s * (1.f / (HH * WW));
}

// ---------------- weight transform: frag-contiguous layout ----------------
// chunk (4096 elems) stores element (row, kk) at:
//   (row>>4)*512 + (kk>>3)*128 + (row&15)*8 + (kk&7)
// so fragment (w,i) for lane l is ONE contiguous dwordx4 at chunk + ((w*4+i)*64 + l)*8.
__global__ void wt_kernel(const float* __restrict__ w1, const float* __restrict__ w2,
                          bf16* __restrict__ wt1r, bf16* __restrict__ wt2r) {
    const int idx = blockIdx.x * 256 + threadIdx.x;
    const int W1N = (int)WT1R_ELEMS;
    if (idx < W1N) {
        int o = idx & 4095;
        int lo = o & 7;
        int l8 = (o >> 3) & 63;
        int rblk = o >> 9;                  // 0..7
        int lh = l8 >> 4, lr = l8 & 15;
        int row = rblk * 16 + lr;
        int kk = lh * 8 + lo;
        int cg = idx >> 12;                 // 0..215
        int e = cg / 36, c = cg - e * 36;
        int q = c / 9, tap = c - q * 9;
        int cin = q * 32 + kk;
        wt1r[idx] = to_bf16(w1[((size_t)(e * CCH + row) * CCH + cin) * 9 + tap]);
    } else if (idx < W1N + (int)WT2R_ELEMS) {
        int j2 = idx - W1N;
        int o = j2 & 4095;
        int lo = o & 7;
        int l8 = (o >> 3) & 63;
        int rblk = o >> 9;
        int lh = l8 >> 4, lr = l8 & 15;
        int row = rblk * 16 + lr;
        int kk = lh * 8 + lo;
        int cg = j2 >> 12;                  // 0..23
        int e = cg >> 2, kc = cg & 3;
        int cin = kc * 32 + kk;
        wt2r[j2] = to_bf16(w2[(size_t)(e * CCH + row) * CCH + cin]);
    }
}

// ---------------- router (verified) ----------------
__global__ void router_kernel(const float* __restrict__ meanbc, const float* __restrict__ Wr,
                              const float* __restrict__ br, int* __restrict__ eidx,
                              float* __restrict__ gval, float* __restrict__ total_out) {
    __shared__ double logits_s[BB][EE];
    __shared__ double probs[BB][EE];
    const int t = threadIdx.x;
    if (t < BB * EE) {
        const int b = t / EE, e = t - (t / EE) * EE;
        double s = (double)br[e];
        for (int c = 0; c < CCH; ++c)
            s += (double)meanbc[b * CCH + c] * (double)Wr[c * EE + e];
        if (s > 10.0) s = 10.0;
        if (s < -10.0) s = -10.0;
        logits_s[b][e] = s;
    }
    __syncthreads();
    if (t < BB) {
        const int b = t;
        double mx = logits_s[b][0];
        for (int e = 1; e < EE; ++e) mx = fmax(mx, logits_s[b][e]);
        double den = 0.0, p[EE];
        for (int e = 0; e < EE; ++e) { p[e] = exp(logits_s[b][e] - mx); den += p[e]; }
        for (int e = 0; e < EE; ++e) {
            p[e] /= den;
            if (p[e] < 1e-6) p[e] = 1e-6;
            if (p[e] > 1.0)  p[e] = 1.0;
            probs[b][e] = p[e];
        }
        int e0 = 0;
        for (int e = 1; e < EE; ++e) if (p[e] > p[e0]) e0 = e;
        int e1 = (e0 == 0) ? 1 : 0;
        for (int e = 0; e < EE; ++e) if (e != e0 && p[e] > p[e1]) e1 = e;
        double s2 = p[e0] + p[e1] + 1e-8;
        eidx[b * 2 + 0] = e0;
        eidx[b * 2 + 1] = e1;
        gval[b * 2 + 0] = (float)(p[e0] / s2);
        gval[b * 2 + 1] = (float)(p[e1] / s2);
    }
    __syncthreads();
    if (t == 0) {
        double usage[EE] = {0, 0, 0, 0, 0, 0};
        double ent = 0.0;
        for (int b = 0; b < BB; ++b) {
            double eb = 0.0;
            for (int e = 0; e < EE; ++e) {
                double pv = probs[b][e];
                usage[e] += pv;
                eb -= pv * log(pv + 1e-10);
            }
            ent += eb;
        }
        ent /= (double)BB;
        double lb = 0.0;
        for (int e = 0; e < EE; ++e) {
            double u = usage[e] / (double)BB - 1.0 / (double)EE;
            lb += u * u;
        }
        *total_out = (float)(lb * 5e-4 - ent * 1e-3);
    }
}

// ---------------- fused MoE conv block ----------------
// R10: NO Abuf. A-operands stream global->register (frag-contiguous wt1r/wt2r, L2-hot
// via XCD swizzle), depth-1 reg prefetch (afc/afn), barrier-free tap loops.
// LDS = Patch 6.9KB (single) + Ht 16KB = 23.3KB. 2-wave blocks, wave = 64 cout x 64 pos.
// Only sync: 2 barriers + vmcnt(0) per patch reload (4x), 3 barriers around gelu/Ht.
__launch_bounds__(128, 2)
__global__ void moe_conv_kernel(const float* __restrict__ x, const bf16* __restrict__ xp,
                                const bf16* __restrict__ wt1r, const bf16* __restrict__ wt2r,
                                const float* __restrict__ b1, const float* __restrict__ b2,
                                const int* __restrict__ eidx, const float* __restrict__ gval,
                                float* __restrict__ out) {
    __shared__ __align__(16) bf16 Patch[108 * 32];     //  6912 B: [rp=py*18+px][4 slots]
    __shared__ __align__(16) bf16 Ht[64 * 128];        // 16384 B: gelu out [pos][16 slots]

    // XCD-aware remap (2304 = 8 * 288): each XCD owns 2 consecutive b's
    const int wgid = blockIdx.x;
    const int work = (wgid & 7) * 288 + (wgid >> 3);
    const int b = work / 144;
    const int tile = work - b * 144;
    const int ty = tile / 6, tx = tile - ty * 6;       // 24 x 6 tiles of 4x16 positions
    const int y0 = ty * 4, x0 = tx * 16;

    const int t = threadIdx.x;                         // 0..127
    const int lane = t & 63;
    const int w = t >> 6;                              // 0..1 : cout half
    const int lr = lane & 15;
    const int lh = lane >> 4;                          // 0..3
    const int lq = lh * 4;

    const bf16* xpb = xp + (size_t)b * HP * HP * CCH;
    const int e0 = eidx[b * 2 + 0], e1 = eidx[b * 2 + 1];
    const float g0 = gval[b * 2 + 0], g1 = gval[b * 2 + 1];

    auto patch_dma = [&](int qn) {                     // own-wave loads; drained by WAITVM0
        #pragma unroll
        for (int it = 0; it < 4; ++it) {
            int m = it * 128 + t;
            if (m < 432) {
                int rp = m >> 2, sl = m & 3;
                int g = sl ^ fsw(rp);
                int py = rp / 18, px = rp - py * 18;
                gload16(xpb + ((size_t)(y0 + py) * HP + (x0 + px)) * CCH + qn * 32 + g * 8,
                        &Patch[(it * 128 + w * 64) * 8]);
            }
        }
    };
    auto loadA = [&](const bf16* chunk, v8bf* af) {    // 4 contiguous dwordx4 / lane
        #pragma unroll
        for (int i = 0; i < 4; ++i)
            af[i] = *reinterpret_cast<const v8bf*>(chunk + ((w * 4 + i) * 64 + lane) * 8);
    };

    f32x4 accA[4][4], accB[4][4];
    #pragma unroll
    for (int i = 0; i < 4; ++i)
        #pragma unroll
        for (int j = 0; j < 4; ++j) {
            f32x4 z = {0.f, 0.f, 0.f, 0.f};
            accA[i][j] = z; accB[i][j] = z;
        }

    // prologue: patch(q0) resident
    patch_dma(0);
    WAITVM0;
    __builtin_amdgcn_s_barrier();

    // ---- conv3x3: q-outer, both experts per q, barrier-free tap loops ----
    for (int q = 0; q < 4; ++q) {
        #pragma unroll
        for (int ek = 0; ek < 2; ++ek) {
            const bf16* wb = wt1r + ((size_t)((ek ? e1 : e0) * 36 + q * 9)) * 4096;
            v8bf afc[4];
            loadA(wb, afc);
            #pragma unroll 1
            for (int tap = 0; tap < 9; ++tap) {
                v8bf afn[4];
                if (tap < 8) loadA(wb + (tap + 1) * 4096, afn);

                const int ry = tap / 3, sx = tap - (tap / 3) * 3;
                v8bf bv[4];
                #pragma unroll
                for (int j = 0; j < 4; ++j) {
                    int rp = (j + ry) * 18 + lr + sx;
                    bv[j] = *reinterpret_cast<const v8bf*>(&Patch[rp * 32 + ((lh ^ fsw(rp)) << 3)]);
                }
                __builtin_amdgcn_s_setprio(1);
                if (ek == 0) {
                    #pragma unroll
                    for (int i = 0; i < 4; ++i)
                        #pragma unroll
                        for (int j = 0; j < 4; ++j)
                            accA[i][j] = __builtin_amdgcn_mfma_f32_16x16x32_bf16(afc[i], bv[j], accA[i][j], 0, 0, 0);
                } else {
                    #pragma unroll
                    for (int i = 0; i < 4; ++i)
                        #pragma unroll
                        for (int j = 0; j < 4; ++j)
                            accB[i][j] = __builtin_amdgcn_mfma_f32_16x16x32_bf16(afc[i], bv[j], accB[i][j], 0, 0, 0);
                }
                __builtin_amdgcn_s_setprio(0);
                if (tap < 8) {
                    #pragma unroll
                    for (int i = 0; i < 4; ++i) afc[i] = afn[i];
                }
            }
        }
        if (q < 3) {                         // single-buffer Patch reload in read-free window
            __builtin_amdgcn_s_barrier();    // all waves done reading Patch[q]
            patch_dma(q + 1);
            WAITVM0;                         // own loads done
            __builtin_amdgcn_s_barrier();    // both waves' loads visible
        }
    }

    // ---- gelu + conv1x1 per expert through single Ht ----
    f32x4 acc1[4][4];
    #pragma unroll
    for (int i = 0; i < 4; ++i)
        #pragma unroll
        for (int j = 0; j < 4; ++j) { f32x4 z = {0.f,0.f,0.f,0.f}; acc1[i][j] = z; }

    #pragma unroll
    for (int ek = 0; ek < 2; ++ek) {
        const int e = ek ? e1 : e0;
        const float g = ek ? g1 : g0;
        const float* b1e = b1 + e * CCH;
        #pragma unroll
        for (int i = 0; i < 4; ++i) {
            const int cb = w * 64 + i * 16 + lq;
            float bias[4];
            #pragma unroll
            for (int q2 = 0; q2 < 4; ++q2) bias[q2] = b1e[cb + q2];
            #pragma unroll
            for (int j = 0; j < 4; ++j) {
                const int pos = j * 16 + lr;
                bf16 hv[4];
                #pragma unroll
                for (int q2 = 0; q2 < 4; ++q2) {
                    float v = (ek ? accB[i][j][q2] : accA[i][j][q2]) + bias[q2];
                    float u = 0.7978845608028654f * (v + 0.044715f * v * v * v);
                    float ex = __expf(2.f * u);
                    float th = (ex - 1.f) / (ex + 1.f);
                    hv[q2] = to_bf16(g * (0.5f * v * (1.f + th)));
                }
                const int slot = (cb >> 3) ^ (pos & 7);
                *reinterpret_cast<uint2*>(&Ht[pos * 128 + slot * 8 + (cb & 7)]) =
                    *reinterpret_cast<uint2*>(hv);
            }
        }
        __syncthreads();                     // publish Ht

        const bf16* w2b = wt2r + (size_t)e * 4 * 4096;
        v8bf afc[4];
        loadA(w2b, afc);
        #pragma unroll 1
        for (int kc = 0; kc < 4; ++kc) {
            v8bf afn[4];
            if (kc < 3) loadA(w2b + (kc + 1) * 4096, afn);
            v8bf bv[4];
            #pragma unroll
            for (int j = 0; j < 4; ++j) {
                int pos = j * 16 + lr;
                int gr = kc * 4 + lh;
                bv[j] = *reinterpret_cast<const v8bf*>(&Ht[pos * 128 + ((gr ^ (pos & 7)) << 3)]);
            }
            __builtin_amdgcn_s_setprio(1);
            #pragma unroll
            for (int i = 0; i < 4; ++i)
                #pragma unroll
                for (int j = 0; j < 4; ++j)
                    acc1[i][j] = __builtin_amdgcn_mfma_f32_16x16x32_bf16(afc[i], bv[j], acc1[i][j], 0, 0, 0);
            __builtin_amdgcn_s_setprio(0);
            if (kc < 3) {
                #pragma unroll
                for (int i = 0; i < 4; ++i) afc[i] = afn[i];
            }
        }
        if (ek == 0) __syncthreads();        // e0's Ht reads done before gelu-e1 overwrite
    }

    // ---- epilogue: out = acc1 + (g0*b2[e0] + g1*b2[e1]) + (g0+g1)*x ----
    const float gsum = g0 + g1;
    #pragma unroll
    for (int i = 0; i < 4; ++i) {
        const int cb = w * 64 + i * 16 + lq;
        float bs[4];
        #pragma unroll
        for (int q2 = 0; q2 < 4; ++q2)
            bs[q2] = g0 * b2[e0 * CCH + cb + q2] + g1 * b2[e1 * CCH + cb + q2];
        #pragma unroll
        for (int j = 0; j < 4; ++j) {
            const int pos = j * 16 + lr;
            const int yy = y0 + (pos >> 4), xx = x0 + (pos & 15);
            #pragma unroll
            for (int q2 = 0; q2 < 4; ++q2) {
                size_t gi = (((size_t)b * CCH + cb + q2) * HH + yy) * WW + xx;
                out[gi] = acc1[i][j][q2] + bs[q2] + gsum * x[gi];
            }
        }
    }
}

extern "C" void kernel_launch(void* const* d_in, const int* in_sizes, int n_in,
                              void* d_out, int out_size, void* d_ws, size_t ws_size,
                              hipStream_t stream) {
    const float* x  = (const float*)d_in[0];
    const float* Wr = (const float*)d_in[1];
    const float* br = (const float*)d_in[2];
    const float* W1 = (const float*)d_in[3];
    const float* b1 = (const float*)d_in[4];
    const float* W2 = (const float*)d_in[5];
    const float* b2 = (const float*)d_in[6];
    float* out = (float*)d_out;

    char* ws = (char*)d_ws;
    bf16* xp    = (bf16*)ws;
    bf16* wt1r  = (bf16*)(ws + XP_BYTES);
    bf16* wt2r  = (bf16*)(ws + XP_BYTES + WT1R_BYTES);
    float* meanpart = (float*)(ws + XP_BYTES + WT1R_BYTES + WT2R_BYTES);
    float* meanbc   = (float*)(ws + XP_BYTES + WT1R_BYTES + WT2R_BYTES + (size_t)BB * HH * CCH * 4);
    int*   eidx     = (int*)(ws + XP_BYTES + WT1R_BYTES + WT2R_BYTES + (size_t)BB * HH * CCH * 4 + BB * CCH * 4);
    float* gvals    = (float*)(ws + XP_BYTES + WT1R_BYTES + WT2R_BYTES + (size_t)BB * HH * CCH * 4 + BB * CCH * 4 + BB * 2 * 4);
    float* total    = out + (size_t)BB * CCH * HH * WW;

    border_kernel<<<BB, 256, 0, stream>>>(xp);
    pad_kernel<<<dim3(HH, BB), 256, 0, stream>>>(x, xp, meanpart);
    reduce_mean_kernel<<<8, 256, 0, stream>>>(meanpart, meanbc);
    wt_kernel<<<(unsigned)((WT1R_ELEMS + WT2R_ELEMS + 255) / 256), 256, 0, stream>>>(W1, W2, wt1r, wt2r);
    router_kernel<<<1, 128, 0, stream>>>(meanbc, Wr, br, eidx, gvals, total);
    moe_conv_kernel<<<2304, 128, 0, stream>>>(x, xp, wt1r, wt2r, b1, b2, eidx, gvals, out);
}